// Round 9
// baseline (88.968 us; speedup 1.0000x reference)
//
#include <hip/hip_runtime.h>

// ---- problem constants ----
#define IN_C  16
#define OUT_C 32
#define NB 2
#define TT 8
#define DD 8
#define HH 32
#define WW 32
#define TP 10
#define DP 10
#define HP 34
#define WPAD 34

// xt layout: [n][tp][dp][hp][icblk(2)][w(34)][ic8] bf16 ; row = 1088 B
#define XT_ROW_B  1088
#define XT_ELEMS  (NB*TP*DP*HP*2*WPAD*8)     // 3,699,200 bf16 = 7,398,400 B
// wt layout: [tap(84 padded)][icblk(2)][oc(32)][ic8] bf16 ; taps 81..83 zeroed
#define WT_TAPS_P 84
#define WT_ELEMS  (WT_TAPS_P*2*OUT_C*8)      // 43,008 bf16 = 86,016 B

#define A_SLAB_B 12288
#define B_CHUNK_B 28672

typedef __bf16 bf16x8 __attribute__((ext_vector_type(8)));
typedef float  f32x4  __attribute__((ext_vector_type(4)));
typedef float  f32x16 __attribute__((ext_vector_type(16)));

__device__ __forceinline__ unsigned short f2bf(float f) {
    unsigned int u = __builtin_bit_cast(unsigned int, f);
    u += 0x7fffu + ((u >> 16) & 1u);       // RNE
    return (unsigned short)(u >> 16);
}

__device__ __forceinline__ void gload16(const void* g, void* l) {
    __builtin_amdgcn_global_load_lds(
        (const __attribute__((address_space(1))) unsigned int*)g,
        (__attribute__((address_space(3))) unsigned int*)l, 16, 0, 0);
}

// ---------------- fused prep: xpose rows + halo zeroing + weight xform ----------------
__global__ __launch_bounds__(256) void prep_kernel(const float* __restrict__ x,
                                                   const float* __restrict__ wsrc,
                                                   unsigned short* __restrict__ xt,
                                                   unsigned short* __restrict__ wt) {
    int b = blockIdx.x;
    int tid = threadIdx.x;
    if (b < 4096) {
        __shared__ unsigned short ls[WW * IN_C];   // [w][c], 1 KiB
        int h = b & 31, d = (b >> 5) & 7, t = (b >> 8) & 7, n = b >> 11;
        int c = tid >> 5, w = tid & 31;
        float v0 = x[((((size_t)(n * IN_C + c)     * TT + t) * DD + d) * HH + h) * WW + w];
        float v1 = x[((((size_t)(n * IN_C + c + 8) * TT + t) * DD + d) * HH + h) * WW + w];
        ls[w * 16 + c]     = f2bf(v0);
        ls[w * 16 + c + 8] = f2bf(v1);
        __syncthreads();
        if (tid < 68) {                 // line = blk*34 + wl
            int blk = tid / 34, wl = tid % 34;
            unsigned char* row = (unsigned char*)xt +
                (size_t)(((n * TP + t + 1) * DP + d + 1) * HP + h + 1) * XT_ROW_B;
            f32x4 val = {0.f, 0.f, 0.f, 0.f};
            if (wl != 0 && wl != 33)
                val = *(const f32x4*)((const unsigned char*)ls + (wl - 1) * 32 + blk * 16);
            *(f32x4*)(row + tid * 16) = val;
        }
    } else if (b < 6800) {
        int j = b - 4096;               // 2704 halo rows
        int n, tp, dp, hp;
        if (j < 1360)      { n = j / 680;  int r = j % 680;  tp = (r / 340) * 9; int r2 = r % 340; dp = r2 / 34;       hp = r2 % 34; }
        else if (j < 2448) { int j2 = j - 1360; n = j2 / 544; int r = j2 % 544; tp = 1 + r / 68;  int r3 = r % 68;  dp = (r3 / 34) * 9; hp = r3 % 34; }
        else               { int j3 = j - 2448; n = j3 / 128; int r = j3 % 128; tp = 1 + r / 16;  int r4 = r % 16;  dp = 1 + r4 / 2;   hp = (r4 & 1) * 33; }
        if (tid < 68) {
            unsigned char* row = (unsigned char*)xt +
                (size_t)(((n * TP + tp) * DP + dp) * HP + hp) * XT_ROW_B;
            f32x4 z = {0.f, 0.f, 0.f, 0.f};
            *(f32x4*)(row + tid * 16) = z;
        }
    } else {
        int idx = (b - 6800) * 256 + tid;   // 0..43007
        int tap = idx >> 9;
        int r = idx & 511;
        int icblk = r >> 8, oc = (r >> 3) & 31, i8 = r & 7;
        int ic = icblk * 8 + i8;
        float v = (tap < 81) ? wsrc[(oc * IN_C + ic) * 81 + tap] : 0.0f;
        wt[idx] = f2bf(v);
    }
}

// ---------------- main: R7 structure, repeated 4x IN-KERNEL for profiling ----------
// Single dispatch ~60us so conv's counters finally appear in the rocprof top-5
// (each conv dispatch alone is ~15us, hidden below the harness's 43us poison
// fills). rep loop is idempotent: acc re-zeroed, same stores each rep; the p=8
// barrier makes the Bs0 restage race-free.
__global__ __launch_bounds__(256, 2) void conv_main_kernel(const unsigned short* __restrict__ xt,
                                                           const unsigned short* __restrict__ wt,
                                                           const float* __restrict__ bias,
                                                           float* __restrict__ out) {
    __shared__ __align__(16) unsigned char As0[A_SLAB_B];
    __shared__ __align__(16) unsigned char As1[A_SLAB_B];
    __shared__ __align__(16) unsigned char Bs0[B_CHUNK_B];
    __shared__ __align__(16) unsigned char Bs1[B_CHUNK_B];

    int bid = blockIdx.x;
    int lb  = (bid & 7) * 64 + (bid >> 3);
    int hb = lb & 3, d = (lb >> 2) & 7, t = (lb >> 5) & 7, n = lb >> 8;
    int h0 = hb * 8;
    int tid  = threadIdx.x;
    int wv   = tid >> 6;               // 0-1 consumers, 2-3 producers
    int lane = tid & 63;
    int l31  = lane & 31;
    int kblk = lane >> 5;

    int ab = kblk * 544 + l31 * 16;
    int bb = kblk * 512 + l31 * 16;

#pragma unroll 1
    for (int rep = 0; rep < 4; ++rep) {
        // ---- prologue: B chunk 0 (1792 lines) + A plane 0 (768 lines) ----
#pragma unroll
        for (int i = 0; i < 7; ++i)
            gload16((const unsigned char*)wt + (tid + i * 256) * 16, Bs0 + (tid + i * 256) * 16);
        {
            const unsigned char* src = (const unsigned char*)xt +
                (size_t)(((n * TP + t) * DP + d) * HP + h0) * XT_ROW_B;
#pragma unroll
            for (int i = 0; i < 3; ++i)
                gload16(src + (tid + i * 256) * 16, As0 + (tid + i * 256) * 16);
        }
        asm volatile("s_waitcnt vmcnt(0)" ::: "memory");
        __syncthreads();

        f32x16 acc[4];
#pragma unroll
        for (int m = 0; m < 4; ++m) acc[m] = {};

#pragma unroll
        for (int p = 0; p < 9; ++p) {
            const int kt = p / 3, ph3 = p % 3;
            if (wv >= 2) {
                int tid2 = tid - 128;
                if (p < 8) {
                    const int ktn = (p + 1) / 3, kdn = (p + 1) % 3;
                    const unsigned char* src = (const unsigned char*)xt +
                        (size_t)(((n * TP + t + ktn) * DP + d + kdn) * HP + h0) * XT_ROW_B;
                    unsigned char* dst = ((p + 1) & 1) ? As1 : As0;
#pragma unroll
                    for (int i = 0; i < 6; ++i)
                        gload16(src + (tid2 + i * 128) * 16, dst + (tid2 + i * 128) * 16);
                }
                if (ph3 <= 1 && kt < 2) {
                    int base = ph3 * 896;
                    const unsigned char* bsrc = (const unsigned char*)wt +
                        (size_t)((kt + 1) * 27 * 64 + base) * 16;
                    unsigned char* bdst = (((kt + 1) & 1) ? Bs1 : Bs0) + base * 16;
#pragma unroll
                    for (int i = 0; i < 7; ++i)
                        gload16(bsrc + (tid2 + i * 128) * 16, bdst + (tid2 + i * 128) * 16);
                }
                asm volatile("s_waitcnt vmcnt(0)" ::: "memory");
            } else {
                const unsigned char* A = (p & 1) ? As1 : As0;
                const unsigned char* B = (kt & 1) ? Bs1 : Bs0;
                const int kd = ph3;

                bf16x8 bf[3][3];
#pragma unroll
                for (int kh = 0; kh < 3; ++kh)
#pragma unroll
                    for (int kw = 0; kw < 3; ++kw)
                        bf[kh][kw] = *(const bf16x8*)(B + ((kd * 9 + kh * 3 + kw) << 10) + bb);

#pragma unroll
                for (int r = 0; r < 6; ++r) {
#pragma unroll
                    for (int kw = 0; kw < 3; ++kw) {
                        bf16x8 a = *(const bf16x8*)(A + (4 * wv + r) * 1088 + ab + kw * 16);
#pragma unroll
                        for (int kh = 0; kh < 3; ++kh) {
                            const int m = r - kh;
                            if (m >= 0 && m < 4)
                                acc[m] = __builtin_amdgcn_mfma_f32_32x32x16_bf16(a, bf[kh][kw], acc[m], 0, 0, 0);
                        }
                    }
                }
            }
            __syncthreads();
        }

        if (wv < 2) {
            float bsv = bias[l31];
#pragma unroll
            for (int m = 0; m < 4; ++m) {
                int oh = h0 + 4 * wv + m;
                float* obase = out + (((((size_t)n * OUT_C + l31) * TT + t) * DD + d) * HH + oh) * WW;
#pragma unroll
                for (int q = 0; q < 4; ++q) {
                    f32x4 v = { acc[m][4 * q + 0] + bsv, acc[m][4 * q + 1] + bsv,
                                acc[m][4 * q + 2] + bsv, acc[m][4 * q + 3] + bsv };
                    *(f32x4*)(obase + 8 * q + 4 * kblk) = v;
                }
            }
        }
        __syncthreads();   // rep boundary: all LDS reads done before restage
    }
}

extern "C" void kernel_launch(void* const* d_in, const int* in_sizes, int n_in,
                              void* d_out, int out_size, void* d_ws, size_t ws_size,
                              hipStream_t stream) {
    const float* x    = (const float*)d_in[0];
    const float* wsrc = (const float*)d_in[1];
    const float* bias = (const float*)d_in[2];
    float* out        = (float*)d_out;

    unsigned short* xt = (unsigned short*)d_ws;
    unsigned short* wt = xt + XT_ELEMS;

    prep_kernel<<<4096 + 2704 + 164, 256, 0, stream>>>(x, wsrc, xt, wt);
    conv_main_kernel<<<NB * TT * DD * 4, 256, 0, stream>>>(xt, wt, bias, out);
}

// Round 10
// 26.547 us; speedup vs baseline: 3.3513x; 3.3513x over previous
//
#include <hip/hip_runtime.h>

// ---- problem constants ----
#define IN_C  16
#define OUT_C 32
#define NB 2
#define TT 8
#define DD 8
#define HH 32
#define WW 32
#define TP 10
#define DP 10
#define HP 34
#define WPAD 34

// xt layout: [n][tp][dp][hp][icblk(2)][w(34)][ic8] bf16 ; row = 1088 B
#define XT_ROW_B  1088
#define XT_ELEMS  (NB*TP*DP*HP*2*WPAD*8)     // 3,699,200 bf16 = 7,398,400 B
// wt layout: [tap(84 padded)][icblk(2)][oc(32)][ic8] bf16 ; taps 81..83 zeroed
#define WT_TAPS_P 84
#define WT_ELEMS  (WT_TAPS_P*2*OUT_C*8)      // 43,008 bf16 = 86,016 B

// conv LDS: A slab = 10 rows x 1088 B padded to 768 lines, dbuf;
// B chunk = 28 taps x 1024 B (1792 lines), dbuf. Total 81,920 B = 2 blocks/CU.
#define A_SLAB_B 12288
#define B_CHUNK_B 28672

typedef __bf16 bf16x8 __attribute__((ext_vector_type(8)));
typedef float  f32x4  __attribute__((ext_vector_type(4)));
typedef float  f32x16 __attribute__((ext_vector_type(16)));

__device__ __forceinline__ unsigned short f2bf(float f) {
    unsigned int u = __builtin_bit_cast(unsigned int, f);
    u += 0x7fffu + ((u >> 16) & 1u);       // RNE
    return (unsigned short)(u >> 16);
}

__device__ __forceinline__ void gload16(const void* g, void* l) {
    __builtin_amdgcn_global_load_lds(
        (const __attribute__((address_space(1))) unsigned int*)g,
        (__attribute__((address_space(3))) unsigned int*)l, 16, 0, 0);
}

// ---------------- fused prep: xpose rows + halo zeroing + weight xform ----------------
__global__ __launch_bounds__(256) void prep_kernel(const float* __restrict__ x,
                                                   const float* __restrict__ wsrc,
                                                   unsigned short* __restrict__ xt,
                                                   unsigned short* __restrict__ wt) {
    int b = blockIdx.x;
    int tid = threadIdx.x;
    if (b < 4096) {
        __shared__ unsigned short ls[WW * IN_C];   // [w][c], 1 KiB
        int h = b & 31, d = (b >> 5) & 7, t = (b >> 8) & 7, n = b >> 11;
        int c = tid >> 5, w = tid & 31;
        float v0 = x[((((size_t)(n * IN_C + c)     * TT + t) * DD + d) * HH + h) * WW + w];
        float v1 = x[((((size_t)(n * IN_C + c + 8) * TT + t) * DD + d) * HH + h) * WW + w];
        ls[w * 16 + c]     = f2bf(v0);
        ls[w * 16 + c + 8] = f2bf(v1);
        __syncthreads();
        if (tid < 68) {                 // line = blk*34 + wl
            int blk = tid / 34, wl = tid % 34;
            unsigned char* row = (unsigned char*)xt +
                (size_t)(((n * TP + t + 1) * DP + d + 1) * HP + h + 1) * XT_ROW_B;
            f32x4 val = {0.f, 0.f, 0.f, 0.f};
            if (wl != 0 && wl != 33)
                val = *(const f32x4*)((const unsigned char*)ls + (wl - 1) * 32 + blk * 16);
            *(f32x4*)(row + tid * 16) = val;
        }
    } else if (b < 6800) {
        int j = b - 4096;               // 2704 halo rows
        int n, tp, dp, hp;
        if (j < 1360)      { n = j / 680;  int r = j % 680;  tp = (r / 340) * 9; int r2 = r % 340; dp = r2 / 34;       hp = r2 % 34; }
        else if (j < 2448) { int j2 = j - 1360; n = j2 / 544; int r = j2 % 544; tp = 1 + r / 68;  int r3 = r % 68;  dp = (r3 / 34) * 9; hp = r3 % 34; }
        else               { int j3 = j - 2448; n = j3 / 128; int r = j3 % 128; tp = 1 + r / 16;  int r4 = r % 16;  dp = 1 + r4 / 2;   hp = (r4 & 1) * 33; }
        if (tid < 68) {
            unsigned char* row = (unsigned char*)xt +
                (size_t)(((n * TP + tp) * DP + dp) * HP + hp) * XT_ROW_B;
            f32x4 z = {0.f, 0.f, 0.f, 0.f};
            *(f32x4*)(row + tid * 16) = z;
        }
    } else {
        int idx = (b - 6800) * 256 + tid;   // 0..43007
        int tap = idx >> 9;
        int r = idx & 511;
        int icblk = r >> 8, oc = (r >> 3) & 31, i8 = r & 7;
        int ic = icblk * 8 + i8;
        float v = (tap < 81) ? wsrc[(oc * IN_C + ic) * 81 + tap] : 0.0f;
        wt[idx] = f2bf(v);
    }
}

// ---------------- main: 32x32x16 MFMA, all-waves compute+stage, counted vmcnt --------
// block = 4 waves (256 thr), ALL compute: wave owns 2 h-rows of the 8-row tile
// (MFMA on all 4 SIMDs). Every phase: issue A-next (3 gload/thr) + B-next (<=4),
// then ds_read + 18 MFMA, then counted vmcnt (A landed, B may fly) + barrier.
// Grid 512 -> 2 blocks/CU, 2 compute waves/SIMD.
__global__ __launch_bounds__(256, 2) void conv_main_kernel(const unsigned short* __restrict__ xt,
                                                           const unsigned short* __restrict__ wt,
                                                           const float* __restrict__ bias,
                                                           float* __restrict__ out) {
    __shared__ __align__(16) unsigned char As0[A_SLAB_B];
    __shared__ __align__(16) unsigned char As1[A_SLAB_B];
    __shared__ __align__(16) unsigned char Bs0[B_CHUNK_B];
    __shared__ __align__(16) unsigned char Bs1[B_CHUNK_B];

    int bid = blockIdx.x;
    int lb  = (bid & 7) * 64 + (bid >> 3);   // XCD swizzle, bijective (512 % 8 == 0)
    int hb = lb & 3, d = (lb >> 2) & 7, t = (lb >> 5) & 7, n = lb >> 8;
    int h0 = hb * 8;
    int tid  = threadIdx.x;
    int wv   = tid >> 6;               // 0..3, owns output rows 2wv, 2wv+1
    int lane = tid & 63;
    int l31  = lane & 31;
    int kblk = lane >> 5;

    int ab = kblk * 544 + l31 * 16;
    int bb = kblk * 512 + l31 * 16;

    // ---- prologue: B chunk 0 (1792 lines) + A plane 0 (768 lines) ----
#pragma unroll
    for (int i = 0; i < 7; ++i)
        gload16((const unsigned char*)wt + (tid + i * 256) * 16, Bs0 + (tid + i * 256) * 16);
    {
        const unsigned char* src = (const unsigned char*)xt +
            (size_t)(((n * TP + t) * DP + d) * HP + h0) * XT_ROW_B;
#pragma unroll
        for (int i = 0; i < 3; ++i)
            gload16(src + (tid + i * 256) * 16, As0 + (tid + i * 256) * 16);
    }
    asm volatile("s_waitcnt vmcnt(0)" ::: "memory");
    __syncthreads();

    f32x16 acc[2];
    acc[0] = {}; acc[1] = {};

#pragma unroll
    for (int p = 0; p < 9; ++p) {
        const int kt = p / 3, ph3 = p % 3;

        // ---- 1. issue staging loads EARLY (A first, then B) ----
        if (p < 8) {
            const int ktn = (p + 1) / 3, kdn = (p + 1) % 3;
            const unsigned char* src = (const unsigned char*)xt +
                (size_t)(((n * TP + t + ktn) * DP + d + kdn) * HP + h0) * XT_ROW_B;
            unsigned char* dst = ((p + 1) & 1) ? As1 : As0;
#pragma unroll
            for (int i = 0; i < 3; ++i)
                gload16(src + (tid + i * 256) * 16, dst + (tid + i * 256) * 16);
        }
        const bool bstage = (kt < 2) && (ph3 <= 1);
        if (bstage) {
            // half of B chunk kt+1: lines [ph3*896, ph3*896+896)
            const int basel = ph3 * 896;
            const unsigned char* bsrc = (const unsigned char*)wt +
                (size_t)((kt + 1) * 27 * 64 + basel) * 16;
            unsigned char* bdst = (((kt + 1) & 1) ? Bs1 : Bs0) + basel * 16;
#pragma unroll
            for (int i = 0; i < 3; ++i)
                gload16(bsrc + (tid + i * 256) * 16, bdst + (tid + i * 256) * 16);
            if (tid < 128)   // tail 128 lines; waves 0,1 fully active (wave-uniform)
                gload16(bsrc + (tid + 768) * 16, bdst + (tid + 768) * 16);
        }

        // ---- 2. compute from A buf[p&1], B chunk buf[kt&1] ----
        const unsigned char* A = (p & 1) ? As1 : As0;
        const unsigned char* B = (kt & 1) ? Bs1 : Bs0;
        const int kd = ph3;

        bf16x8 bf[3][3];
#pragma unroll
        for (int kh = 0; kh < 3; ++kh)
#pragma unroll
            for (int kw = 0; kw < 3; ++kw)
                bf[kh][kw] = *(const bf16x8*)(B + ((kd * 9 + kh * 3 + kw) << 10) + bb);

#pragma unroll
        for (int rr = 0; rr < 4; ++rr) {       // input rows 2wv+rr
#pragma unroll
            for (int kw = 0; kw < 3; ++kw) {
                bf16x8 a = *(const bf16x8*)(A + (2 * wv + rr) * 1088 + ab + kw * 16);
#pragma unroll
                for (int kh = 0; kh < 3; ++kh) {
                    const int m = rr - kh;
                    if (m >= 0 && m < 2)
                        acc[m] = __builtin_amdgcn_mfma_f32_32x32x16_bf16(a, bf[kh][kw], acc[m], 0, 0, 0);
                }
            }
        }

        // ---- 3. counted drain: A must land; in-flight B (newest 4) may keep flying ----
        if (bstage)
            asm volatile("s_waitcnt vmcnt(4)" ::: "memory");
        else
            asm volatile("s_waitcnt vmcnt(0)" ::: "memory");
        __syncthreads();
    }

    // ---- epilogue: col(oc)=l31, row(w)=(reg&3)+8*(reg>>2)+4*kblk ----
    float bsv = bias[l31];
#pragma unroll
    for (int m = 0; m < 2; ++m) {
        int oh = h0 + 2 * wv + m;
        float* obase = out + (((((size_t)n * OUT_C + l31) * TT + t) * DD + d) * HH + oh) * WW;
#pragma unroll
        for (int q = 0; q < 4; ++q) {
            f32x4 v = { acc[m][4 * q + 0] + bsv, acc[m][4 * q + 1] + bsv,
                        acc[m][4 * q + 2] + bsv, acc[m][4 * q + 3] + bsv };
            *(f32x4*)(obase + 8 * q + 4 * kblk) = v;
        }
    }
}

extern "C" void kernel_launch(void* const* d_in, const int* in_sizes, int n_in,
                              void* d_out, int out_size, void* d_ws, size_t ws_size,
                              hipStream_t stream) {
    const float* x    = (const float*)d_in[0];
    const float* wsrc = (const float*)d_in[1];
    const float* bias = (const float*)d_in[2];
    float* out        = (float*)d_out;

    unsigned short* xt = (unsigned short*)d_ws;
    unsigned short* wt = xt + XT_ELEMS;

    prep_kernel<<<4096 + 2704 + 164, 256, 0, stream>>>(x, wsrc, xt, wt);
    conv_main_kernel<<<NB * TT * DD * 4, 256, 0, stream>>>(xt, wt, bias, out);
}